// Round 1
// baseline (4182.204 us; speedup 1.0000x reference)
//
#include <hip/hip_runtime.h>
#include <cmath>

#define N_NODES   100000
#define N_EDGES   3200000
#define D_FEAT    512
#define HIDDEN    16
#define N_CLASSES 7

typedef __attribute__((ext_vector_type(4))) float  f32x4;
typedef __attribute__((ext_vector_type(8))) short  bf16x8;

__device__ __forceinline__ short f2bf(float f) {
    union { float f; unsigned u; } v; v.f = f;
    unsigned r = v.u + 0x7fffu + ((v.u >> 16) & 1u);   // RNE
    return (short)(r >> 16);
}

// ---------------- degree (in-degree over dst; +1 self-loop added later) ----
__global__ __launch_bounds__(256) void k_deg(const int* __restrict__ dst,
                                             unsigned* __restrict__ deg) {
    int e = blockIdx.x * 256 + threadIdx.x;
    if (e < N_EDGES) atomicAdd(&deg[dst[e]], 1u);
}

__global__ __launch_bounds__(256) void k_dinv(const unsigned* __restrict__ deg,
                                              float* __restrict__ dinv) {
    int i = blockIdx.x * 256 + threadIdx.x;
    if (i < N_NODES) dinv[i] = rsqrtf((float)(deg[i] + 1u));
}

// ---------------- GEMM1: h1 = x@W1 (bf16 MFMA, fp32 acc); m1 = dinv^2*h1 ----
// One wave per 16-row tile. B fragments (W1, bf16, transposed) preloaded from
// LDS into 64 VGPRs once per wave; A streamed from global fp32 and converted
// in-register. Memory-bound: 204.8 MB x read.
__global__ __launch_bounds__(256) void k_gemm1(const float* __restrict__ x,
                                               const float* __restrict__ w1,
                                               const float* __restrict__ dinv,
                                               float* __restrict__ h1,
                                               float* __restrict__ m1) {
    // W1^T as bf16: row n (out feature), 512 k. Pad 512->520 shorts: row
    // stride 1040B = 65*16B (keeps 16B alignment), bank delta 260 dw ≡ 4 mod 32
    // -> 2-way conflict max (free).
    __shared__ __align__(16) short w1t[16][520];
    int tid = threadIdx.x;
    for (int idx = tid; idx < D_FEAT * HIDDEN; idx += 256) {
        int k = idx >> 4, n = idx & 15;
        w1t[n][k] = f2bf(w1[idx]);
    }
    __syncthreads();

    int lane = tid & 63, wid = tid >> 6;
    int m  = lane & 15;        // A-row carried / C-col written
    int kg = lane >> 4;        // k-group (quad)

    bf16x8 bfrag[16];
    #pragma unroll
    for (int ks = 0; ks < 16; ++ks)
        bfrag[ks] = *(const bf16x8*)&w1t[m][ks * 32 + kg * 8];

    int tile = blockIdx.x * 4 + wid;
    if (tile >= (N_NODES / 16)) return;

    const f32x4* xr = (const f32x4*)(x + (size_t)(tile * 16 + m) * D_FEAT);
    f32x4 acc = {0.f, 0.f, 0.f, 0.f};
    #pragma unroll
    for (int ks = 0; ks < 16; ++ks) {
        f32x4 x0 = xr[ks * 8 + kg * 2];
        f32x4 x1 = xr[ks * 8 + kg * 2 + 1];
        bf16x8 a;
        a[0] = f2bf(x0[0]); a[1] = f2bf(x0[1]); a[2] = f2bf(x0[2]); a[3] = f2bf(x0[3]);
        a[4] = f2bf(x1[0]); a[5] = f2bf(x1[1]); a[6] = f2bf(x1[2]); a[7] = f2bf(x1[3]);
        acc = __builtin_amdgcn_mfma_f32_16x16x32_bf16(a, bfrag[ks], acc, 0, 0, 0);
    }
    // C layout: col = lane&15, row = (lane>>4)*4 + reg  [m89-verified]
    size_t base = (size_t)tile * 256;
    #pragma unroll
    for (int r = 0; r < 4; ++r) {
        int rr = kg * 4 + r;
        float v  = acc[r];
        float di = dinv[tile * 16 + rr];
        h1[base + rr * 16 + m] = v;
        m1[base + rr * 16 + m] = di * di * v;   // self-loop init (no memset)
    }
}

// ---------------- scatter layer 1: m1[dst] += w_e * h1[src] ----------------
__global__ __launch_bounds__(256) void k_scat1(const int* __restrict__ src,
                                               const int* __restrict__ dst,
                                               const float* __restrict__ dinv,
                                               const float* __restrict__ h1,
                                               float* __restrict__ m1) {
    int e = blockIdx.x * 256 + threadIdx.x;
    if (e >= N_EDGES) return;
    int s = src[e], d = dst[e];
    float we = dinv[s] * dinv[d];
    const f32x4* hs = (const f32x4*)(h1 + (size_t)s * 16);
    f32x4 v0 = hs[0], v1 = hs[1], v2 = hs[2], v3 = hs[3];
    float* md = m1 + (size_t)d * 16;
    unsafeAtomicAdd(md + 0,  we * v0[0]);
    unsafeAtomicAdd(md + 1,  we * v0[1]);
    unsafeAtomicAdd(md + 2,  we * v0[2]);
    unsafeAtomicAdd(md + 3,  we * v0[3]);
    unsafeAtomicAdd(md + 4,  we * v1[0]);
    unsafeAtomicAdd(md + 5,  we * v1[1]);
    unsafeAtomicAdd(md + 6,  we * v1[2]);
    unsafeAtomicAdd(md + 7,  we * v1[3]);
    unsafeAtomicAdd(md + 8,  we * v2[0]);
    unsafeAtomicAdd(md + 9,  we * v2[1]);
    unsafeAtomicAdd(md + 10, we * v2[2]);
    unsafeAtomicAdd(md + 11, we * v2[3]);
    unsafeAtomicAdd(md + 12, we * v3[0]);
    unsafeAtomicAdd(md + 13, we * v3[1]);
    unsafeAtomicAdd(md + 14, we * v3[2]);
    unsafeAtomicAdd(md + 15, we * v3[3]);
}

// ------- layer 2: h = relu(m1+b1); h2 = h@W2; m2 = dinv^2*h2 (self-loop) ----
__global__ __launch_bounds__(256) void k_layer2(const float* __restrict__ m1,
                                                const float* __restrict__ dinv,
                                                const float* __restrict__ w2,
                                                const float* __restrict__ b1,
                                                float* __restrict__ h2,
                                                float* __restrict__ m2) {
    int i = blockIdx.x * 256 + threadIdx.x;
    if (i >= N_NODES) return;
    const float* mr = m1 + (size_t)i * 16;
    float h[16];
    #pragma unroll
    for (int j = 0; j < 16; ++j) h[j] = fmaxf(mr[j] + b1[j], 0.f);
    float di = dinv[i];
    float di2 = di * di;
    float* h2r = h2 + (size_t)i * 8;
    float* m2r = m2 + (size_t)i * 8;
    #pragma unroll
    for (int c = 0; c < N_CLASSES; ++c) {
        float o = 0.f;
        #pragma unroll
        for (int j = 0; j < 16; ++j) o += h[j] * w2[j * N_CLASSES + c];
        h2r[c] = o;
        m2r[c] = di2 * o;
    }
    h2r[7] = 0.f; m2r[7] = 0.f;
}

// ---------------- scatter layer 2: m2[dst] += w_e * h2[src] ----------------
__global__ __launch_bounds__(256) void k_scat2(const int* __restrict__ src,
                                               const int* __restrict__ dst,
                                               const float* __restrict__ dinv,
                                               const float* __restrict__ h2,
                                               float* __restrict__ m2) {
    int e = blockIdx.x * 256 + threadIdx.x;
    if (e >= N_EDGES) return;
    int s = src[e], d = dst[e];
    float we = dinv[s] * dinv[d];
    const f32x4* hs = (const f32x4*)(h2 + (size_t)s * 8);
    f32x4 v0 = hs[0], v1 = hs[1];
    float* md = m2 + (size_t)d * 8;
    unsafeAtomicAdd(md + 0, we * v0[0]);
    unsafeAtomicAdd(md + 1, we * v0[1]);
    unsafeAtomicAdd(md + 2, we * v0[2]);
    unsafeAtomicAdd(md + 3, we * v0[3]);
    unsafeAtomicAdd(md + 4, we * v1[0]);
    unsafeAtomicAdd(md + 5, we * v1[1]);
    unsafeAtomicAdd(md + 6, we * v1[2]);
}

// ---------------- logits = m2 + b2; out = log_softmax ----------------------
__global__ __launch_bounds__(256) void k_final(const float* __restrict__ m2,
                                               const float* __restrict__ b2,
                                               float* __restrict__ out) {
    int i = blockIdx.x * 256 + threadIdx.x;
    if (i >= N_NODES) return;
    const float* mr = m2 + (size_t)i * 8;
    float v[N_CLASSES];
    float mx = -1e30f;
    #pragma unroll
    for (int c = 0; c < N_CLASSES; ++c) { v[c] = mr[c] + b2[c]; mx = fmaxf(mx, v[c]); }
    float sum = 0.f;
    #pragma unroll
    for (int c = 0; c < N_CLASSES; ++c) sum += __expf(v[c] - mx);
    float lse = __logf(sum);
    float* o = out + (size_t)i * N_CLASSES;
    #pragma unroll
    for (int c = 0; c < N_CLASSES; ++c) o[c] = v[c] - mx - lse;
}

extern "C" void kernel_launch(void* const* d_in, const int* in_sizes, int n_in,
                              void* d_out, int out_size, void* d_ws, size_t ws_size,
                              hipStream_t stream) {
    const float* x  = (const float*)d_in[0];
    const int*   ei = (const int*)d_in[1];      // [2, E] int (harness-converted)
    const float* w1 = (const float*)d_in[2];
    const float* b1 = (const float*)d_in[3];
    const float* w2 = (const float*)d_in[4];
    const float* b2 = (const float*)d_in[5];
    float* out = (float*)d_out;

    const int* src = ei;
    const int* dst = ei + N_EDGES;

    // workspace carve (floats): ~19.1 MB total
    float*    dinv = (float*)d_ws;              // 100000 (padded to 102400)
    float*    h1   = dinv + 102400;             // 1,600,000
    float*    m1   = h1   + 1600000;            // 1,600,000
    float*    h2   = m1   + 1600000;            // 800,000 (stride 8)
    float*    m2   = h2   + 800000;             // 800,000 (stride 8)
    unsigned* deg  = (unsigned*)(m2 + 800000);  // 100,000

    const int EB = (N_EDGES + 255) / 256;       // 12500
    const int NB = (N_NODES + 255) / 256;       // 391
    const int GB = (N_NODES / 16 + 3) / 4;      // 1563 (4 waves/block, 1 tile/wave)

    hipMemsetAsync(deg, 0, N_NODES * sizeof(unsigned), stream);
    k_deg   <<<EB, 256, 0, stream>>>(dst, deg);
    k_dinv  <<<NB, 256, 0, stream>>>(deg, dinv);
    k_gemm1 <<<GB, 256, 0, stream>>>(x, w1, dinv, h1, m1);
    k_scat1 <<<EB, 256, 0, stream>>>(src, dst, dinv, h1, m1);
    k_layer2<<<NB, 256, 0, stream>>>(m1, dinv, w2, b1, h2, m2);
    k_scat2 <<<EB, 256, 0, stream>>>(src, dst, dinv, h2, m2);
    k_final <<<NB, 256, 0, stream>>>(m2, b2, out);
}

// Round 2
// 842.080 us; speedup vs baseline: 4.9665x; 4.9665x over previous
//
#include <hip/hip_runtime.h>
#include <cmath>

#define N_NODES   100000
#define N_EDGES   3200000
#define D_FEAT    512
#define HIDDEN    16
#define N_CLASSES 7

typedef __attribute__((ext_vector_type(4))) float  f32x4;
typedef __attribute__((ext_vector_type(8))) short  bf16x8;

__device__ __forceinline__ short f2bf(float f) {
    union { float f; unsigned u; } v; v.f = f;
    unsigned r = v.u + 0x7fffu + ((v.u >> 16) & 1u);   // RNE
    return (short)(r >> 16);
}

// ---------------- degree (in-degree over dst; +1 self-loop in dinv) --------
__global__ __launch_bounds__(256) void k_deg(const int* __restrict__ dst,
                                             unsigned* __restrict__ deg) {
    int e = blockIdx.x * 256 + threadIdx.x;
    if (e < N_EDGES) atomicAdd(&deg[dst[e]], 1u);
}

__global__ __launch_bounds__(256) void k_dinv(const unsigned* __restrict__ deg,
                                              float* __restrict__ dinv) {
    int i = blockIdx.x * 256 + threadIdx.x;
    if (i < N_NODES) dinv[i] = rsqrtf((float)(deg[i] + 1u));
}

// ---------------- exclusive scan of deg -> row_start (3 kernels) -----------
__global__ __launch_bounds__(256) void k_scan_blocks(const unsigned* __restrict__ deg,
                                                     unsigned* __restrict__ row_excl,
                                                     unsigned* __restrict__ part) {
    __shared__ unsigned t0[256];
    int t = threadIdx.x, i = blockIdx.x * 256 + t;
    unsigned v = (i < N_NODES) ? deg[i] : 0u;
    t0[t] = v; __syncthreads();
    #pragma unroll
    for (int off = 1; off < 256; off <<= 1) {
        unsigned add = (t >= off) ? t0[t - off] : 0u;
        __syncthreads();
        t0[t] += add;
        __syncthreads();
    }
    if (i < N_NODES) row_excl[i] = t0[t] - v;
    if (t == 255) part[blockIdx.x] = t0[t];
}

__global__ __launch_bounds__(512) void k_scan_part(unsigned* __restrict__ part,
                                                   unsigned* __restrict__ part_scan,
                                                   int nparts) {
    __shared__ unsigned t0[512];
    int t = threadIdx.x;
    unsigned v = (t < nparts) ? part[t] : 0u;
    t0[t] = v; __syncthreads();
    #pragma unroll
    for (int off = 1; off < 512; off <<= 1) {
        unsigned add = (t >= off) ? t0[t - off] : 0u;
        __syncthreads();
        t0[t] += add;
        __syncthreads();
    }
    if (t < nparts) part_scan[t] = t0[t] - v;
}

__global__ __launch_bounds__(256) void k_scan_add(const unsigned* __restrict__ row_excl,
                                                  const unsigned* __restrict__ part_scan,
                                                  unsigned* __restrict__ row_start,
                                                  unsigned* __restrict__ cursor) {
    int i = blockIdx.x * 256 + threadIdx.x;
    if (i < N_NODES) {
        unsigned r = row_excl[i] + part_scan[blockIdx.x];
        row_start[i] = r;
        cursor[i]    = r;
    }
}

// ---------------- CSR fill: bucket src indices by dst ----------------------
__global__ __launch_bounds__(256) void k_fill(const int* __restrict__ src,
                                              const int* __restrict__ dst,
                                              unsigned* __restrict__ cursor,
                                              int* __restrict__ csr_src) {
    int e = blockIdx.x * 256 + threadIdx.x;
    if (e >= N_EDGES) return;
    unsigned pos = atomicAdd(&cursor[dst[e]], 1u);
    csr_src[pos] = src[e];
}

// ---------------- GEMM1: h1 = x@W1 (bf16 MFMA, fp32 acc) -------------------
__global__ __launch_bounds__(256) void k_gemm1(const float* __restrict__ x,
                                               const float* __restrict__ w1,
                                               float* __restrict__ h1) {
    __shared__ __align__(16) short w1t[16][520];
    int tid = threadIdx.x;
    for (int idx = tid; idx < D_FEAT * HIDDEN; idx += 256) {
        int k = idx >> 4, n = idx & 15;
        w1t[n][k] = f2bf(w1[idx]);
    }
    __syncthreads();

    int lane = tid & 63, wid = tid >> 6;
    int m  = lane & 15;        // A-row carried / C-col written
    int kg = lane >> 4;        // k-group (quad)

    bf16x8 bfrag[16];
    #pragma unroll
    for (int ks = 0; ks < 16; ++ks)
        bfrag[ks] = *(const bf16x8*)&w1t[m][ks * 32 + kg * 8];

    int tile = blockIdx.x * 4 + wid;
    if (tile >= (N_NODES / 16)) return;

    const f32x4* xr = (const f32x4*)(x + (size_t)(tile * 16 + m) * D_FEAT);
    f32x4 acc = {0.f, 0.f, 0.f, 0.f};
    #pragma unroll
    for (int ks = 0; ks < 16; ++ks) {
        f32x4 x0 = xr[ks * 8 + kg * 2];
        f32x4 x1 = xr[ks * 8 + kg * 2 + 1];
        bf16x8 a;
        a[0] = f2bf(x0[0]); a[1] = f2bf(x0[1]); a[2] = f2bf(x0[2]); a[3] = f2bf(x0[3]);
        a[4] = f2bf(x1[0]); a[5] = f2bf(x1[1]); a[6] = f2bf(x1[2]); a[7] = f2bf(x1[3]);
        acc = __builtin_amdgcn_mfma_f32_16x16x32_bf16(a, bfrag[ks], acc, 0, 0, 0);
    }
    // C layout: col = lane&15, row = (lane>>4)*4 + reg  [m89-verified]
    size_t base = (size_t)tile * 256;
    #pragma unroll
    for (int r = 0; r < 4; ++r) {
        int rr = kg * 4 + r;
        h1[base + rr * 16 + m] = acc[r];
    }
}

// ---------------- gather layer 1: m1[i] = sum_e w_e h1[src] + self ---------
// 16 lanes per node (lane j = feature j); 16-edge coalesced prefetch + shfl.
__global__ __launch_bounds__(256) void k_gather1(const int* __restrict__ csr_src,
                                                 const unsigned* __restrict__ row_start,
                                                 const unsigned* __restrict__ deg,
                                                 const float* __restrict__ dinv,
                                                 const float* __restrict__ h1,
                                                 float* __restrict__ m1) {
    int tid  = threadIdx.x;
    int j    = tid & 15;
    int grp  = tid >> 4;                    // 0..15 within block
    int node = blockIdx.x * 16 + grp;       // grid 6250 -> exactly 100000

    float di  = dinv[node];
    float acc = di * di * h1[(size_t)node * 16 + j];   // self-loop
    unsigned start = row_start[node];
    unsigned end   = start + deg[node];
    for (unsigned e = start; e < end; e += 16) {
        unsigned idx = e + (unsigned)j;
        int   sv = (idx < end) ? csr_src[idx] : 0;
        float dv = (idx < end) ? dinv[sv] : 0.f;
        int cnt = (int)min(16u, end - e);
        for (int t = 0; t < cnt; ++t) {
            int   s  = __shfl(sv, t, 16);
            float ws = __shfl(dv, t, 16);
            acc += (di * ws) * h1[(size_t)s * 16 + j];
        }
    }
    m1[(size_t)node * 16 + j] = acc;
}

// ------- layer 2 transform: h2 = relu(m1+b1) @ W2 (stride-8 rows) ----------
__global__ __launch_bounds__(256) void k_layer2(const float* __restrict__ m1,
                                                const float* __restrict__ w2,
                                                const float* __restrict__ b1,
                                                float* __restrict__ h2) {
    int i = blockIdx.x * 256 + threadIdx.x;
    if (i >= N_NODES) return;
    const float* mr = m1 + (size_t)i * 16;
    float h[16];
    #pragma unroll
    for (int j = 0; j < 16; ++j) h[j] = fmaxf(mr[j] + b1[j], 0.f);
    float* h2r = h2 + (size_t)i * 8;
    #pragma unroll
    for (int c = 0; c < N_CLASSES; ++c) {
        float o = 0.f;
        #pragma unroll
        for (int j = 0; j < 16; ++j) o += h[j] * w2[j * N_CLASSES + c];
        h2r[c] = o;
    }
    h2r[7] = 0.f;
}

// ------- gather layer 2 + bias + log_softmax fused -------------------------
// 8 lanes per node (lane j = class j, lane 7 idle-ish).
__global__ __launch_bounds__(256) void k_gather2(const int* __restrict__ csr_src,
                                                 const unsigned* __restrict__ row_start,
                                                 const unsigned* __restrict__ deg,
                                                 const float* __restrict__ dinv,
                                                 const float* __restrict__ h2,
                                                 const float* __restrict__ b2,
                                                 float* __restrict__ out) {
    int tid  = threadIdx.x;
    int j    = tid & 7;
    int grp  = tid >> 3;                    // 0..31 within block
    int node = blockIdx.x * 32 + grp;       // grid 3125 -> exactly 100000

    float di  = dinv[node];
    float acc = di * di * h2[(size_t)node * 8 + j];    // self-loop
    unsigned start = row_start[node];
    unsigned end   = start + deg[node];
    for (unsigned e = start; e < end; e += 8) {
        unsigned idx = e + (unsigned)j;
        int   sv = (idx < end) ? csr_src[idx] : 0;
        float dv = (idx < end) ? dinv[sv] : 0.f;
        int cnt = (int)min(8u, end - e);
        for (int t = 0; t < cnt; ++t) {
            int   s  = __shfl(sv, t, 8);
            float ws = __shfl(dv, t, 8);
            acc += (di * ws) * h2[(size_t)s * 8 + j];
        }
    }
    float logit = (j < N_CLASSES) ? acc + b2[j] : -1e30f;
    float mx = logit;
    #pragma unroll
    for (int mk = 1; mk < 8; mk <<= 1) mx = fmaxf(mx, __shfl_xor(mx, mk, 8));
    float ex = (j < N_CLASSES) ? __expf(logit - mx) : 0.f;
    float sum = ex;
    #pragma unroll
    for (int mk = 1; mk < 8; mk <<= 1) sum += __shfl_xor(sum, mk, 8);
    if (j < N_CLASSES)
        out[(size_t)node * N_CLASSES + j] = logit - mx - __logf(sum);
}

extern "C" void kernel_launch(void* const* d_in, const int* in_sizes, int n_in,
                              void* d_out, int out_size, void* d_ws, size_t ws_size,
                              hipStream_t stream) {
    const float* x  = (const float*)d_in[0];
    const int*   ei = (const int*)d_in[1];
    const float* w1 = (const float*)d_in[2];
    const float* b1 = (const float*)d_in[3];
    const float* w2 = (const float*)d_in[4];
    const float* b2 = (const float*)d_in[5];
    float* out = (float*)d_out;

    const int* src = ei;
    const int* dst = ei + N_EDGES;

    // workspace carve (~31 MB)
    float*    dinv      = (float*)d_ws;                 // 102400
    float*    h1        = dinv + 102400;                // 1,600,000
    float*    m1        = h1   + 1600000;               // 1,600,000
    float*    h2        = m1   + 1600000;               //   800,000
    unsigned* deg       = (unsigned*)(h2 + 800000);     // 102,400
    unsigned* row_excl  = deg       + 102400;           // 102,400
    unsigned* row_start = row_excl  + 102400;           // 102,400
    unsigned* cursor    = row_start + 102400;           // 102,400
    unsigned* part      = cursor    + 102400;           // 512
    unsigned* part_scan = part      + 512;              // 512
    int*      csr_src   = (int*)(part_scan + 512);      // 3,200,000

    const int EB  = (N_EDGES + 255) / 256;   // 12500
    const int NB  = (N_NODES + 255) / 256;   // 391
    const int GB  = (N_NODES / 16 + 3) / 4;  // 1563 (gemm tiles)

    hipMemsetAsync(deg, 0, N_NODES * sizeof(unsigned), stream);
    k_deg        <<<EB,   256, 0, stream>>>(dst, deg);
    k_dinv       <<<NB,   256, 0, stream>>>(deg, dinv);
    k_gemm1      <<<GB,   256, 0, stream>>>(x, w1, h1);
    k_scan_blocks<<<NB,   256, 0, stream>>>(deg, row_excl, part);
    k_scan_part  <<<1,    512, 0, stream>>>(part, part_scan, NB);
    k_scan_add   <<<NB,   256, 0, stream>>>(row_excl, part_scan, row_start, cursor);
    k_fill       <<<EB,   256, 0, stream>>>(src, dst, cursor, csr_src);
    k_gather1    <<<6250, 256, 0, stream>>>(csr_src, row_start, deg, dinv, h1, m1);
    k_layer2     <<<NB,   256, 0, stream>>>(m1, w2, b1, h2);
    k_gather2    <<<3125, 256, 0, stream>>>(csr_src, row_start, deg, dinv, h2, b2, out);
}

// Round 3
// 584.184 us; speedup vs baseline: 7.1591x; 1.4415x over previous
//
#include <hip/hip_runtime.h>
#include <cmath>

#define N_NODES   100000
#define N_EDGES   3200000
#define D_FEAT    512
#define HIDDEN    16
#define N_CLASSES 7

#define NCHUNK 391                 // pass-1 blocks, 8192 edges each
#define CHUNK  8192
#define NBKT   391                 // buckets of 256 nodes (dst>>8)
#define NSCAN  (NBKT * NCHUNK)     // 152881
#define NSB    ((NSCAN + 255) / 256) // 598

typedef __attribute__((ext_vector_type(4))) float  f32x4;
typedef __attribute__((ext_vector_type(8))) short  bf16x8;

__device__ __forceinline__ short f2bf(float f) {
    union { float f; unsigned u; } v; v.f = f;
    unsigned r = v.u + 0x7fffu + ((v.u >> 16) & 1u);   // RNE
    return (short)(r >> 16);
}

// ---------------- pass 1a: per-chunk bucket histogram (LDS atomics only) ---
__global__ __launch_bounds__(256) void k_hist1(const int* __restrict__ dst,
                                               unsigned* __restrict__ hist) {
    __shared__ unsigned h[NBKT];
    int t = threadIdx.x, b = blockIdx.x;
    for (int i = t; i < NBKT; i += 256) h[i] = 0u;
    __syncthreads();
    int base = b * CHUNK;
    #pragma unroll 4
    for (int k = 0; k < 32; ++k) {
        int e = base + k * 256 + t;
        if (e < N_EDGES) atomicAdd(&h[((unsigned)dst[e]) >> 8], 1u);
    }
    __syncthreads();
    for (int i = t; i < NBKT; i += 256)
        hist[(size_t)i * NCHUNK + b] = h[i];   // bin-major for global scan
}

// ---------------- exclusive scan over NSCAN entries (3 kernels) ------------
__global__ __launch_bounds__(256) void k_scan_blocks(const unsigned* __restrict__ in,
                                                     unsigned* __restrict__ out_excl,
                                                     unsigned* __restrict__ part, int n) {
    __shared__ unsigned t0[256];
    int t = threadIdx.x, i = blockIdx.x * 256 + t;
    unsigned v = (i < n) ? in[i] : 0u;
    t0[t] = v; __syncthreads();
    #pragma unroll
    for (int off = 1; off < 256; off <<= 1) {
        unsigned add = (t >= off) ? t0[t - off] : 0u;
        __syncthreads();
        t0[t] += add;
        __syncthreads();
    }
    if (i < n) out_excl[i] = t0[t] - v;
    if (t == 255) part[blockIdx.x] = t0[t];
}

__global__ __launch_bounds__(1024) void k_scan_part(unsigned* __restrict__ part,
                                                    unsigned* __restrict__ part_scan,
                                                    int nparts) {
    __shared__ unsigned t0[1024];
    int t = threadIdx.x;
    unsigned v = (t < nparts) ? part[t] : 0u;
    t0[t] = v; __syncthreads();
    #pragma unroll
    for (int off = 1; off < 1024; off <<= 1) {
        unsigned add = (t >= off) ? t0[t - off] : 0u;
        __syncthreads();
        t0[t] += add;
        __syncthreads();
    }
    if (t < nparts) part_scan[t] = t0[t] - v;
}

__global__ __launch_bounds__(256) void k_scan_add(unsigned* __restrict__ excl,
                                                  const unsigned* __restrict__ part_scan,
                                                  int n) {
    int i = blockIdx.x * 256 + threadIdx.x;
    if (i < n) excl[i] += part_scan[blockIdx.x];   // in-place -> final offsets
}

// ---------------- pass 1b: scatter edges into bucket-major order -----------
__global__ __launch_bounds__(256) void k_scatter1(const int* __restrict__ src,
                                                  const int* __restrict__ dst,
                                                  const unsigned* __restrict__ hist_scan,
                                                  unsigned* __restrict__ sorted_src,
                                                  unsigned char* __restrict__ sorted_b) {
    __shared__ unsigned cur[NBKT];
    int t = threadIdx.x, b = blockIdx.x;
    for (int i = t; i < NBKT; i += 256) cur[i] = hist_scan[(size_t)i * NCHUNK + b];
    __syncthreads();
    int base = b * CHUNK;
    #pragma unroll 4
    for (int k = 0; k < 32; ++k) {
        int e = base + k * 256 + t;
        if (e < N_EDGES) {
            unsigned d = (unsigned)dst[e];
            unsigned pos = atomicAdd(&cur[d >> 8], 1u);   // LDS atomic
            sorted_src[pos] = (unsigned)src[e];
            sorted_b[pos]   = (unsigned char)(d & 255u);
        }
    }
}

// -------- pass 2: per-bucket exact-dst sort -> deg, row_start, csr_src -----
__global__ __launch_bounds__(256) void k_bucket(const unsigned* __restrict__ sorted_src,
                                                const unsigned char* __restrict__ sorted_b,
                                                const unsigned* __restrict__ hist_scan,
                                                unsigned* __restrict__ deg,
                                                unsigned* __restrict__ row_start,
                                                int* __restrict__ csr_src) {
    __shared__ unsigned hist[256], scan[256], cur[256];
    int t = threadIdx.x, k = blockIdx.x;
    unsigned rs = hist_scan[(size_t)k * NCHUNK];
    unsigned re = (k + 1 < NBKT) ? hist_scan[(size_t)(k + 1) * NCHUNK] : N_EDGES;
    hist[t] = 0u;
    __syncthreads();
    for (unsigned i = rs + t; i < re; i += 256)
        atomicAdd(&hist[sorted_b[i]], 1u);
    __syncthreads();
    unsigned v = hist[t];
    scan[t] = v;
    __syncthreads();
    #pragma unroll
    for (int off = 1; off < 256; off <<= 1) {
        unsigned add = (t >= off) ? scan[t - off] : 0u;
        __syncthreads();
        scan[t] += add;
        __syncthreads();
    }
    unsigned excl = scan[t] - v;
    int node = k * 256 + t;
    if (node < N_NODES) { deg[node] = v; row_start[node] = rs + excl; }
    cur[t] = rs + excl;
    __syncthreads();
    for (unsigned i = rs + t; i < re; i += 256) {
        unsigned pos = atomicAdd(&cur[sorted_b[i]], 1u);  // LDS atomic
        csr_src[pos] = (int)sorted_src[i];
    }
}

__global__ __launch_bounds__(256) void k_dinv(const unsigned* __restrict__ deg,
                                              float* __restrict__ dinv) {
    int i = blockIdx.x * 256 + threadIdx.x;
    if (i < N_NODES) dinv[i] = rsqrtf((float)(deg[i] + 1u));
}

// ---------------- GEMM1: h1 = x@W1 (bf16 MFMA, fp32 acc) -------------------
__global__ __launch_bounds__(256) void k_gemm1(const float* __restrict__ x,
                                               const float* __restrict__ w1,
                                               float* __restrict__ h1) {
    __shared__ __align__(16) short w1t[16][520];
    int tid = threadIdx.x;
    for (int idx = tid; idx < D_FEAT * HIDDEN; idx += 256) {
        int k = idx >> 4, n = idx & 15;
        w1t[n][k] = f2bf(w1[idx]);
    }
    __syncthreads();

    int lane = tid & 63, wid = tid >> 6;
    int m  = lane & 15;
    int kg = lane >> 4;

    bf16x8 bfrag[16];
    #pragma unroll
    for (int ks = 0; ks < 16; ++ks)
        bfrag[ks] = *(const bf16x8*)&w1t[m][ks * 32 + kg * 8];

    int tile = blockIdx.x * 4 + wid;
    if (tile >= (N_NODES / 16)) return;

    const f32x4* xr = (const f32x4*)(x + (size_t)(tile * 16 + m) * D_FEAT);
    f32x4 acc = {0.f, 0.f, 0.f, 0.f};
    #pragma unroll
    for (int ks = 0; ks < 16; ++ks) {
        f32x4 x0 = xr[ks * 8 + kg * 2];
        f32x4 x1 = xr[ks * 8 + kg * 2 + 1];
        bf16x8 a;
        a[0] = f2bf(x0[0]); a[1] = f2bf(x0[1]); a[2] = f2bf(x0[2]); a[3] = f2bf(x0[3]);
        a[4] = f2bf(x1[0]); a[5] = f2bf(x1[1]); a[6] = f2bf(x1[2]); a[7] = f2bf(x1[3]);
        acc = __builtin_amdgcn_mfma_f32_16x16x32_bf16(a, bfrag[ks], acc, 0, 0, 0);
    }
    size_t base = (size_t)tile * 256;
    #pragma unroll
    for (int r = 0; r < 4; ++r) {
        int rr = kg * 4 + r;
        h1[base + rr * 16 + m] = acc[r];
    }
}

// ---------------- gather layer 1 -------------------------------------------
__global__ __launch_bounds__(256) void k_gather1(const int* __restrict__ csr_src,
                                                 const unsigned* __restrict__ row_start,
                                                 const unsigned* __restrict__ deg,
                                                 const float* __restrict__ dinv,
                                                 const float* __restrict__ h1,
                                                 float* __restrict__ m1) {
    int tid  = threadIdx.x;
    int j    = tid & 15;
    int grp  = tid >> 4;
    int node = blockIdx.x * 16 + grp;

    float di  = dinv[node];
    float acc = di * di * h1[(size_t)node * 16 + j];   // self-loop
    unsigned start = row_start[node];
    unsigned end   = start + deg[node];
    for (unsigned e = start; e < end; e += 16) {
        unsigned idx = e + (unsigned)j;
        int   sv = (idx < end) ? csr_src[idx] : 0;
        float dv = (idx < end) ? dinv[sv] : 0.f;
        int cnt = (int)min(16u, end - e);
        for (int t = 0; t < cnt; ++t) {
            int   s  = __shfl(sv, t, 16);
            float ws = __shfl(dv, t, 16);
            acc += (di * ws) * h1[(size_t)s * 16 + j];
        }
    }
    m1[(size_t)node * 16 + j] = acc;
}

// ------- layer 2 transform: h2 = relu(m1+b1) @ W2 (stride-8 rows) ----------
__global__ __launch_bounds__(256) void k_layer2(const float* __restrict__ m1,
                                                const float* __restrict__ w2,
                                                const float* __restrict__ b1,
                                                float* __restrict__ h2) {
    int i = blockIdx.x * 256 + threadIdx.x;
    if (i >= N_NODES) return;
    const float* mr = m1 + (size_t)i * 16;
    float h[16];
    #pragma unroll
    for (int j = 0; j < 16; ++j) h[j] = fmaxf(mr[j] + b1[j], 0.f);
    float* h2r = h2 + (size_t)i * 8;
    #pragma unroll
    for (int c = 0; c < N_CLASSES; ++c) {
        float o = 0.f;
        #pragma unroll
        for (int j = 0; j < 16; ++j) o += h[j] * w2[j * N_CLASSES + c];
        h2r[c] = o;
    }
    h2r[7] = 0.f;
}

// ------- gather layer 2 + bias + log_softmax fused -------------------------
__global__ __launch_bounds__(256) void k_gather2(const int* __restrict__ csr_src,
                                                 const unsigned* __restrict__ row_start,
                                                 const unsigned* __restrict__ deg,
                                                 const float* __restrict__ dinv,
                                                 const float* __restrict__ h2,
                                                 const float* __restrict__ b2,
                                                 float* __restrict__ out) {
    int tid  = threadIdx.x;
    int j    = tid & 7;
    int grp  = tid >> 3;
    int node = blockIdx.x * 32 + grp;

    float di  = dinv[node];
    float acc = di * di * h2[(size_t)node * 8 + j];    // self-loop
    unsigned start = row_start[node];
    unsigned end   = start + deg[node];
    for (unsigned e = start; e < end; e += 8) {
        unsigned idx = e + (unsigned)j;
        int   sv = (idx < end) ? csr_src[idx] : 0;
        float dv = (idx < end) ? dinv[sv] : 0.f;
        int cnt = (int)min(8u, end - e);
        for (int t = 0; t < cnt; ++t) {
            int   s  = __shfl(sv, t, 8);
            float ws = __shfl(dv, t, 8);
            acc += (di * ws) * h2[(size_t)s * 8 + j];
        }
    }
    float logit = (j < N_CLASSES) ? acc + b2[j] : -1e30f;
    float mx = logit;
    #pragma unroll
    for (int mk = 1; mk < 8; mk <<= 1) mx = fmaxf(mx, __shfl_xor(mx, mk, 8));
    float ex = (j < N_CLASSES) ? __expf(logit - mx) : 0.f;
    float sum = ex;
    #pragma unroll
    for (int mk = 1; mk < 8; mk <<= 1) sum += __shfl_xor(sum, mk, 8);
    if (j < N_CLASSES)
        out[(size_t)node * N_CLASSES + j] = logit - mx - __logf(sum);
}

extern "C" void kernel_launch(void* const* d_in, const int* in_sizes, int n_in,
                              void* d_out, int out_size, void* d_ws, size_t ws_size,
                              hipStream_t stream) {
    const float* x  = (const float*)d_in[0];
    const int*   ei = (const int*)d_in[1];
    const float* w1 = (const float*)d_in[2];
    const float* b1 = (const float*)d_in[3];
    const float* w2 = (const float*)d_in[4];
    const float* b2 = (const float*)d_in[5];
    float* out = (float*)d_out;

    const int* src = ei;
    const int* dst = ei + N_EDGES;

    // workspace carve (u32 units), ~44 MB total
    unsigned* w32       = (unsigned*)d_ws;
    float*    dinv      = (float*)(w32 + 0);            // 102,400
    float*    h1        = (float*)(w32 + 102400);       // 1,600,000
    float*    m1        = (float*)(w32 + 1702400);      // 1,600,000
    unsigned* deg       = w32 + 3302400;                // 102,400
    unsigned* row_start = w32 + 3404800;                // 102,400
    unsigned* hist_raw  = w32 + 3507200;                // 153,600
    unsigned* hist_sc   = w32 + 3660800;                // 153,600 (excl scan, in-place add)
    unsigned* part      = w32 + 3814400;                // 1,024
    unsigned* part_scan = w32 + 3815424;                // 1,024
    unsigned* sorted_src= w32 + 3816448;                // 3,200,000
    int*      csr_src   = (int*)(w32 + 7016448);        // 3,200,000
    unsigned char* sorted_b = (unsigned char*)(w32 + 10216448); // 3,200,000 B
    float*    h2        = (float*)sorted_src;           // alias: free after k_bucket

    const int NB = (N_NODES + 255) / 256;    // 391
    const int GB = (N_NODES / 16 + 3) / 4;   // 1563

    k_gemm1      <<<GB,     256,  0, stream>>>(x, w1, h1);
    k_hist1      <<<NCHUNK, 256,  0, stream>>>(dst, hist_raw);
    k_scan_blocks<<<NSB,    256,  0, stream>>>(hist_raw, hist_sc, part, NSCAN);
    k_scan_part  <<<1,      1024, 0, stream>>>(part, part_scan, NSB);
    k_scan_add   <<<NSB,    256,  0, stream>>>(hist_sc, part_scan, NSCAN);
    k_scatter1   <<<NCHUNK, 256,  0, stream>>>(src, dst, hist_sc, sorted_src, sorted_b);
    k_bucket     <<<NBKT,   256,  0, stream>>>(sorted_src, sorted_b, hist_sc, deg, row_start, csr_src);
    k_dinv       <<<NB,     256,  0, stream>>>(deg, dinv);
    k_gather1    <<<6250,   256,  0, stream>>>(csr_src, row_start, deg, dinv, h1, m1);
    k_layer2     <<<NB,     256,  0, stream>>>(m1, w2, b1, h2);
    k_gather2    <<<3125,   256,  0, stream>>>(csr_src, row_start, deg, dinv, h2, b2, out);
}

// Round 4
// 556.608 us; speedup vs baseline: 7.5137x; 1.0495x over previous
//
#include <hip/hip_runtime.h>
#include <cmath>

#define N_NODES   100000
#define N_EDGES   3200000
#define D_FEAT    512
#define HIDDEN    16
#define N_CLASSES 7

#define NCHUNK 391                   // pass-1 blocks, 8192 edges each
#define CHUNK  8192
#define NBKT   391                   // buckets of 256 nodes (dst>>8)
#define NSCAN  (NBKT * NCHUNK)       // 152881
#define NSB    ((NSCAN + 255) / 256) // 598

typedef __attribute__((ext_vector_type(4))) float  f32x4;
typedef __attribute__((ext_vector_type(8))) short  bf16x8;

__device__ __forceinline__ short f2bf(float f) {
    union { float f; unsigned u; } v; v.f = f;
    unsigned r = v.u + 0x7fffu + ((v.u >> 16) & 1u);   // RNE
    return (short)(r >> 16);
}

// ---------------- pass 1a: per-chunk bucket histogram (LDS atomics only) ---
__global__ __launch_bounds__(256) void k_hist1(const int* __restrict__ dst,
                                               unsigned* __restrict__ hist) {
    __shared__ unsigned h[NBKT];
    int t = threadIdx.x, b = blockIdx.x;
    for (int i = t; i < NBKT; i += 256) h[i] = 0u;
    __syncthreads();
    int base = b * CHUNK;
    #pragma unroll 4
    for (int k = 0; k < 32; ++k) {
        int e = base + k * 256 + t;
        if (e < N_EDGES) atomicAdd(&h[((unsigned)dst[e]) >> 8], 1u);
    }
    __syncthreads();
    for (int i = t; i < NBKT; i += 256)
        hist[(size_t)i * NCHUNK + b] = h[i];   // bin-major for global scan
}

// ---------------- exclusive scan over NSCAN entries (3 kernels) ------------
__global__ __launch_bounds__(256) void k_scan_blocks(const unsigned* __restrict__ in,
                                                     unsigned* __restrict__ out_excl,
                                                     unsigned* __restrict__ part, int n) {
    __shared__ unsigned t0[256];
    int t = threadIdx.x, i = blockIdx.x * 256 + t;
    unsigned v = (i < n) ? in[i] : 0u;
    t0[t] = v; __syncthreads();
    #pragma unroll
    for (int off = 1; off < 256; off <<= 1) {
        unsigned add = (t >= off) ? t0[t - off] : 0u;
        __syncthreads();
        t0[t] += add;
        __syncthreads();
    }
    if (i < n) out_excl[i] = t0[t] - v;
    if (t == 255) part[blockIdx.x] = t0[t];
}

__global__ __launch_bounds__(1024) void k_scan_part(unsigned* __restrict__ part,
                                                    unsigned* __restrict__ part_scan,
                                                    int nparts) {
    __shared__ unsigned t0[1024];
    int t = threadIdx.x;
    unsigned v = (t < nparts) ? part[t] : 0u;
    t0[t] = v; __syncthreads();
    #pragma unroll
    for (int off = 1; off < 1024; off <<= 1) {
        unsigned add = (t >= off) ? t0[t - off] : 0u;
        __syncthreads();
        t0[t] += add;
        __syncthreads();
    }
    if (t < nparts) part_scan[t] = t0[t] - v;
}

__global__ __launch_bounds__(256) void k_scan_add(unsigned* __restrict__ excl,
                                                  const unsigned* __restrict__ part_scan,
                                                  int n) {
    int i = blockIdx.x * 256 + threadIdx.x;
    if (i < n) excl[i] += part_scan[blockIdx.x];
}

// ---------------- pass 1b: scatter edges into bucket-major order -----------
__global__ __launch_bounds__(256) void k_scatter1(const int* __restrict__ src,
                                                  const int* __restrict__ dst,
                                                  const unsigned* __restrict__ hist_scan,
                                                  unsigned* __restrict__ sorted_src,
                                                  unsigned char* __restrict__ sorted_b) {
    __shared__ unsigned cur[NBKT];
    int t = threadIdx.x, b = blockIdx.x;
    for (int i = t; i < NBKT; i += 256) cur[i] = hist_scan[(size_t)i * NCHUNK + b];
    __syncthreads();
    int base = b * CHUNK;
    #pragma unroll 4
    for (int k = 0; k < 32; ++k) {
        int e = base + k * 256 + t;
        if (e < N_EDGES) {
            unsigned d = (unsigned)dst[e];
            unsigned pos = atomicAdd(&cur[d >> 8], 1u);   // LDS atomic
            sorted_src[pos] = (unsigned)src[e];
            sorted_b[pos]   = (unsigned char)(d & 255u);
        }
    }
}

// -------- pass 2: per-bucket exact-dst sort -> deg, row_start, dinv, csr ---
__global__ __launch_bounds__(256) void k_bucket(const unsigned* __restrict__ sorted_src,
                                                const unsigned char* __restrict__ sorted_b,
                                                const unsigned* __restrict__ hist_scan,
                                                unsigned* __restrict__ deg,
                                                unsigned* __restrict__ row_start,
                                                float* __restrict__ dinv,
                                                int* __restrict__ csr_src) {
    __shared__ unsigned hist[256], scan[256], cur[256];
    int t = threadIdx.x, k = blockIdx.x;
    unsigned rs = hist_scan[(size_t)k * NCHUNK];
    unsigned re = (k + 1 < NBKT) ? hist_scan[(size_t)(k + 1) * NCHUNK] : N_EDGES;
    hist[t] = 0u;
    __syncthreads();
    for (unsigned i = rs + t; i < re; i += 256)
        atomicAdd(&hist[sorted_b[i]], 1u);
    __syncthreads();
    unsigned v = hist[t];
    scan[t] = v;
    __syncthreads();
    #pragma unroll
    for (int off = 1; off < 256; off <<= 1) {
        unsigned add = (t >= off) ? scan[t - off] : 0u;
        __syncthreads();
        scan[t] += add;
        __syncthreads();
    }
    unsigned excl = scan[t] - v;
    int node = k * 256 + t;
    if (node < N_NODES) {
        deg[node]       = v;
        row_start[node] = rs + excl;
        dinv[node]      = rsqrtf((float)(v + 1u));
    }
    cur[t] = rs + excl;
    __syncthreads();
    for (unsigned i = rs + t; i < re; i += 256) {
        unsigned pos = atomicAdd(&cur[sorted_b[i]], 1u);  // LDS atomic
        csr_src[pos] = (int)sorted_src[i];
    }
}

// ------- GEMM1: h1p = dinv .* (x@W1)  (bf16 MFMA, fp32 acc) ----------------
__global__ __launch_bounds__(256) void k_gemm1(const float* __restrict__ x,
                                               const float* __restrict__ w1,
                                               const float* __restrict__ dinv,
                                               float* __restrict__ h1p) {
    __shared__ __align__(16) short w1t[16][520];
    int tid = threadIdx.x;
    for (int idx = tid; idx < D_FEAT * HIDDEN; idx += 256) {
        int k = idx >> 4, n = idx & 15;
        w1t[n][k] = f2bf(w1[idx]);
    }
    __syncthreads();

    int lane = tid & 63, wid = tid >> 6;
    int m  = lane & 15;
    int kg = lane >> 4;

    bf16x8 bfrag[16];
    #pragma unroll
    for (int ks = 0; ks < 16; ++ks)
        bfrag[ks] = *(const bf16x8*)&w1t[m][ks * 32 + kg * 8];

    int tile = blockIdx.x * 4 + wid;
    if (tile >= (N_NODES / 16)) return;

    const f32x4* xr = (const f32x4*)(x + (size_t)(tile * 16 + m) * D_FEAT);
    f32x4 acc = {0.f, 0.f, 0.f, 0.f};
    #pragma unroll
    for (int ks = 0; ks < 16; ++ks) {
        f32x4 x0 = xr[ks * 8 + kg * 2];
        f32x4 x1 = xr[ks * 8 + kg * 2 + 1];
        bf16x8 a;
        a[0] = f2bf(x0[0]); a[1] = f2bf(x0[1]); a[2] = f2bf(x0[2]); a[3] = f2bf(x0[3]);
        a[4] = f2bf(x1[0]); a[5] = f2bf(x1[1]); a[6] = f2bf(x1[2]); a[7] = f2bf(x1[3]);
        acc = __builtin_amdgcn_mfma_f32_16x16x32_bf16(a, bfrag[ks], acc, 0, 0, 0);
    }
    // C layout: col = lane&15, row = (lane>>4)*4 + reg  [m89-verified]
    size_t base = (size_t)tile * 256;
    #pragma unroll
    for (int r = 0; r < 4; ++r) {
        int rr = kg * 4 + r;
        h1p[base + rr * 16 + m] = dinv[tile * 16 + rr] * acc[r];
    }
}

// ------- gather layer 1: g1[i][j] = h1p[i][j] + sum_e h1p[src_e][j] --------
// One wave per node; lane = slot*16 + feat; 16 edges per main iteration.
__global__ __launch_bounds__(256) void k_gather1(const int* __restrict__ csr_src,
                                                 const unsigned* __restrict__ row_start,
                                                 const unsigned* __restrict__ deg,
                                                 const float* __restrict__ h1p,
                                                 float* __restrict__ g1) {
    int tid  = threadIdx.x;
    int lane = tid & 63;
    int node = blockIdx.x * 4 + (tid >> 6);
    int j  = lane & 15;
    int sl = lane >> 4;          // 0..3

    unsigned start = row_start[node];
    unsigned end   = start + deg[node];

    float acc = (sl == 0) ? h1p[(size_t)node * 16 + j] : 0.f;   // self term
    unsigned e = start;
    for (; e + 16 <= end; e += 16) {
        int s0 = csr_src[e      + sl];
        int s1 = csr_src[e + 4  + sl];
        int s2 = csr_src[e + 8  + sl];
        int s3 = csr_src[e + 12 + sl];
        float v0 = h1p[(size_t)s0 * 16 + j];
        float v1 = h1p[(size_t)s1 * 16 + j];
        float v2 = h1p[(size_t)s2 * 16 + j];
        float v3 = h1p[(size_t)s3 * 16 + j];
        acc += v0; acc += v1; acc += v2; acc += v3;
    }
    for (; e < end; e += 4) {
        unsigned idx = e + (unsigned)sl;
        float v = 0.f;
        if (idx < end) v = h1p[(size_t)csr_src[idx] * 16 + j];
        acc += v;
    }
    acc += __shfl_down(acc, 32);
    acc += __shfl_down(acc, 16);
    if (sl == 0) g1[(size_t)node * 16 + j] = acc;
}

// ------- layer 2: h2p = dinv .* (relu(dinv.*g1 + b1) @ W2) -----------------
__global__ __launch_bounds__(256) void k_layer2(const float* __restrict__ g1,
                                                const float* __restrict__ dinv,
                                                const float* __restrict__ w2,
                                                const float* __restrict__ b1,
                                                float* __restrict__ h2p) {
    int i = blockIdx.x * 256 + threadIdx.x;
    if (i >= N_NODES) return;
    float di = dinv[i];
    const float* gr = g1 + (size_t)i * 16;
    float h[16];
    #pragma unroll
    for (int j = 0; j < 16; ++j) h[j] = fmaxf(di * gr[j] + b1[j], 0.f);
    float* h2r = h2p + (size_t)i * 8;
    #pragma unroll
    for (int c = 0; c < N_CLASSES; ++c) {
        float o = 0.f;
        #pragma unroll
        for (int j = 0; j < 16; ++j) o += h[j] * w2[j * N_CLASSES + c];
        h2r[c] = di * o;
    }
    h2r[7] = 0.f;
}

// ------- gather layer 2 + bias + log_softmax fused -------------------------
// One wave per node; lane = slot*8 + class; 32 edges per main iteration.
__global__ __launch_bounds__(256) void k_gather2(const int* __restrict__ csr_src,
                                                 const unsigned* __restrict__ row_start,
                                                 const unsigned* __restrict__ deg,
                                                 const float* __restrict__ dinv,
                                                 const float* __restrict__ h2p,
                                                 const float* __restrict__ b2,
                                                 float* __restrict__ out) {
    int tid  = threadIdx.x;
    int lane = tid & 63;
    int node = blockIdx.x * 4 + (tid >> 6);
    int j  = lane & 7;
    int sl = lane >> 3;          // 0..7

    unsigned start = row_start[node];
    unsigned end   = start + deg[node];

    float acc = (sl == 0) ? h2p[(size_t)node * 8 + j] : 0.f;    // self term
    unsigned e = start;
    for (; e + 32 <= end; e += 32) {
        int s0 = csr_src[e      + sl];
        int s1 = csr_src[e + 8  + sl];
        int s2 = csr_src[e + 16 + sl];
        int s3 = csr_src[e + 24 + sl];
        float v0 = h2p[(size_t)s0 * 8 + j];
        float v1 = h2p[(size_t)s1 * 8 + j];
        float v2 = h2p[(size_t)s2 * 8 + j];
        float v3 = h2p[(size_t)s3 * 8 + j];
        acc += v0; acc += v1; acc += v2; acc += v3;
    }
    for (; e < end; e += 8) {
        unsigned idx = e + (unsigned)sl;
        float v = 0.f;
        if (idx < end) v = h2p[(size_t)csr_src[idx] * 8 + j];
        acc += v;
    }
    acc += __shfl_down(acc, 32);
    acc += __shfl_down(acc, 16);
    acc += __shfl_down(acc, 8);
    // lanes 0..7 now hold the aggregate for classes 0..7 (class 7 slot = 0)
    float di = dinv[node];
    float logit = (j < N_CLASSES) ? di * acc + b2[j] : -1e30f;
    float mx = logit;
    #pragma unroll
    for (int mk = 1; mk < 8; mk <<= 1) mx = fmaxf(mx, __shfl_xor(mx, mk, 8));
    float ex = (j < N_CLASSES) ? __expf(logit - mx) : 0.f;
    float sum = ex;
    #pragma unroll
    for (int mk = 1; mk < 8; mk <<= 1) sum += __shfl_xor(sum, mk, 8);
    if (sl == 0 && j < N_CLASSES)
        out[(size_t)node * N_CLASSES + j] = logit - mx - __logf(sum);
}

extern "C" void kernel_launch(void* const* d_in, const int* in_sizes, int n_in,
                              void* d_out, int out_size, void* d_ws, size_t ws_size,
                              hipStream_t stream) {
    const float* x  = (const float*)d_in[0];
    const int*   ei = (const int*)d_in[1];
    const float* w1 = (const float*)d_in[2];
    const float* b1 = (const float*)d_in[3];
    const float* w2 = (const float*)d_in[4];
    const float* b2 = (const float*)d_in[5];
    float* out = (float*)d_out;

    const int* src = ei;
    const int* dst = ei + N_EDGES;

    // workspace carve (u32 units)
    unsigned* w32       = (unsigned*)d_ws;
    float*    dinv      = (float*)(w32 + 0);            // 102,400
    float*    h1p       = (float*)(w32 + 102400);       // 1,600,000
    float*    g1        = (float*)(w32 + 1702400);      // 1,600,000
    unsigned* deg       = w32 + 3302400;                // 102,400
    unsigned* row_start = w32 + 3404800;                // 102,400
    unsigned* hist_raw  = w32 + 3507200;                // 153,600
    unsigned* hist_sc   = w32 + 3660800;                // 153,600
    unsigned* part      = w32 + 3814400;                // 1,024
    unsigned* part_scan = w32 + 3815424;                // 1,024
    unsigned* sorted_src= w32 + 3816448;                // 3,200,000
    int*      csr_src   = (int*)(w32 + 7016448);        // 3,200,000
    unsigned char* sorted_b = (unsigned char*)(w32 + 10216448); // 3,200,000 B
    float*    h2p       = (float*)sorted_src;           // alias: free after k_bucket

    const int NB = (N_NODES + 255) / 256;    // 391
    const int GB = (N_NODES / 16 + 3) / 4;   // 1563

    k_hist1      <<<NCHUNK, 256,  0, stream>>>(dst, hist_raw);
    k_scan_blocks<<<NSB,    256,  0, stream>>>(hist_raw, hist_sc, part, NSCAN);
    k_scan_part  <<<1,      1024, 0, stream>>>(part, part_scan, NSB);
    k_scan_add   <<<NSB,    256,  0, stream>>>(hist_sc, part_scan, NSCAN);
    k_scatter1   <<<NCHUNK, 256,  0, stream>>>(src, dst, hist_sc, sorted_src, sorted_b);
    k_bucket     <<<NBKT,   256,  0, stream>>>(sorted_src, sorted_b, hist_sc, deg, row_start, dinv, csr_src);
    k_gemm1      <<<GB,     256,  0, stream>>>(x, w1, dinv, h1p);
    k_gather1    <<<25000,  256,  0, stream>>>(csr_src, row_start, deg, h1p, g1);
    k_layer2     <<<NB,     256,  0, stream>>>(g1, dinv, w2, b1, h2p);
    k_gather2    <<<25000,  256,  0, stream>>>(csr_src, row_start, deg, dinv, h2p, b2, out);
}